// Round 2
// baseline (22329.161 us; speedup 1.0000x reference)
//
#include <hip/hip_runtime.h>
#include <hip/hip_bf16.h>

typedef __hip_bfloat16 bf16_t;
typedef short bf16x8 __attribute__((ext_vector_type(8)));   // 8 bf16 bit patterns (4 VGPRs)
typedef float floatx4 __attribute__((ext_vector_type(4)));

#define B_SZ 128
#define T_SZ 1024
#define D_SZ 256
#define H_SZ 1024
#define O_SZ 10
#define G4H  (4 * H_SZ)     // 4096 gate columns
#define KTOT 1280           // H + D
#define NKH  32             // H / 32 (K-steps on the recurrent part)
#define UPW  16             // hidden units per WG
#define CPW  64             // gate columns per WG (4 gates x 16 units)
#define NWG  64             // one WG per CU, 64 CUs active
#define KLDS 39             // K-steps resident in LDS (the 40th lives in registers)
#define KSTR (CPW * 32)     // elements per K-step in LDS (2048)
#define FLAG_STRIDE 32      // uints between per-block flags (128 B, own cacheline)

// Zero hbuf[0] (h_{-1} = 0) and the 64 barrier flags. Kernel-end writeback
// pushes these to the coherence point before lstm_main starts.
__global__ void init_state(unsigned int* __restrict__ hz, unsigned int* __restrict__ flags) {
    int idx = blockIdx.x * 256 + threadIdx.x;   // 256 x 256 = 65536
    hz[idx] = 0u;                               // 65536 uints = hbuf[0] (128x1024 bf16)
    if (idx < NWG) flags[idx * FLAG_STRIDE] = 0u;
}

// Agent-coherent 16B load: bypasses (possibly stale) L1/L2, reads the MALL
// coherence point. r1 proved cached+buffer_inv is SLOWER - keep direct path.
__device__ __forceinline__ bf16x8 load_h16(const bf16_t* p) {
    bf16x8 r;
    asm volatile("global_load_dwordx4 %0, %1, off sc0 sc1"
                 : "=v"(r) : "v"(p) : "memory");
    return r;
}
__device__ __forceinline__ void vmwait0() {
    asm volatile("s_waitcnt vmcnt(0)" ::: "memory");
}

// Grid barrier with NO cache-maintenance ops (r0-proven):
//   release = vmcnt(0) drain of this wave's sc1 h-stores (already at MALL),
//   arrival = one relaxed agent store to the block's own 128B-spaced flag,
//   wait    = each thread polls flag (tid&63); all 64 flags covered.
__device__ __forceinline__ void grid_barrier(unsigned int* __restrict__ flags,
                                             unsigned int tgt) {
    vmwait0();          // this wave's h stores completed to coherence point
    __syncthreads();    // all waves of the block drained
    if (threadIdx.x == 0)
        __hip_atomic_store(flags + blockIdx.x * FLAG_STRIDE, tgt,
                           __ATOMIC_RELAXED, __HIP_MEMORY_SCOPE_AGENT);
    unsigned int* w = flags + (threadIdx.x & (NWG - 1)) * FLAG_STRIDE;
    while (__hip_atomic_load(w, __ATOMIC_RELAXED, __HIP_MEMORY_SCOPE_AGENT) < tgt)
        __builtin_amdgcn_s_sleep(8);
    __syncthreads();    // whole block has observed all 64 arrivals
}

// Convert 8 consecutive fp32 to a bf16x8 MFMA fragment (RNE via __float2bfloat16).
__device__ __forceinline__ bf16x8 cvt8(const float* __restrict__ p) {
    floatx4 a = *(const floatx4*)p;
    floatx4 b = *(const floatx4*)(p + 4);
    union { bf16_t h; short s; } u;
    bf16x8 r;
    u.h = __float2bfloat16(a[0]); r[0] = u.s;
    u.h = __float2bfloat16(a[1]); r[1] = u.s;
    u.h = __float2bfloat16(a[2]); r[2] = u.s;
    u.h = __float2bfloat16(a[3]); r[3] = u.s;
    u.h = __float2bfloat16(b[0]); r[4] = u.s;
    u.h = __float2bfloat16(b[1]); r[5] = u.s;
    u.h = __float2bfloat16(b[2]); r[6] = u.s;
    u.h = __float2bfloat16(b[3]); r[7] = u.s;
    return r;
}

#define MFMA(a, b, c) __builtin_amdgcn_mfma_f32_16x16x32_bf16((a), (b), (c), 0, 0, 0)

// ---------------------------------------------------------------------------
// 64 WGs x 256 threads (4 waves). WG jg owns hidden units jg*16..jg*16+15
// (64 gate cols) for all 128 batch rows. Total h broadcast: 64 x 256 KB =
// 16 MB/step (was 64 MB with 256 WGs) -> 4x less fabric traffic.
// Each wave: 2 row-tiles (rows wave*32..+31) x 4 col-tiles; the 4 col-tiles
// ARE the 4 gates, so i/f/g/o for a (row,unit) land in one thread: the cell
// update is fully in-register - no G staging LDS, no syncthreads, and the
// 3.0e8 LDS bank conflicts from G are gone.
// Weights: 39/40 K-steps in 156 KB dynamic LDS, K-step 39 in registers.
// ---------------------------------------------------------------------------
__global__ void __launch_bounds__(256, 1)
lstm_main(const float* __restrict__ x,      // [B][T][D] fp32
          const float* __restrict__ Wx,     // [D][4H]   fp32
          const float* __restrict__ Wh,     // [H][4H]   fp32
          const float* __restrict__ bias,   // [4H]      fp32
          bf16_t* __restrict__ hbuf,        // [2][128][1024] bf16 in d_ws
          unsigned int* __restrict__ flags) { // NWG x FLAG_STRIDE uints in d_ws
    extern __shared__ bf16_t Wlds[];        // [KLDS][64 cols][32 k] = 159744 B

    const int tid  = threadIdx.x;
    const int jg   = blockIdx.x;
    const int lane = tid & 63;
    const int wave = tid >> 6;
    const int u    = lane & 15;          // unit within WG / MFMA col
    const int qk   = (lane >> 4) * 8;    // k-offset within 32 (A/B quad)

    // ---- Stage weight K-steps 0..38 into LDS (fp32 -> bf16). ----
    // Layout: [kk][c][q*8+j], k = kk*32 + q*8 + j, c = gate*16 + unit.
    for (int k = tid; k < KLDS * 32; k += 256) {
        int kk = k >> 5, q = (k >> 3) & 3, j = k & 7;
        bf16_t* dst = Wlds + kk * KSTR + q * 8 + j;
        const float* row = (k < H_SZ) ? (Wh + (size_t)k * G4H)
                                      : (Wx + (size_t)(k - H_SZ) * G4H);
        #pragma unroll
        for (int g = 0; g < 4; ++g) {
            const float* src = row + g * H_SZ + jg * UPW;
            #pragma unroll
            for (int uu = 0; uu < 16; uu += 4) {
                floatx4 w = *(const floatx4*)(src + uu);
                #pragma unroll
                for (int v = 0; v < 4; ++v)
                    dst[(g * 16 + uu + v) * 32] = __float2bfloat16(w[v]);
            }
        }
    }

    // ---- K-step 39 (x-part rows 224..255) B-fragments in registers. ----
    bf16x8 bx[4];
    #pragma unroll
    for (int ct = 0; ct < 4; ++ct) {
        union { bf16_t h; short s; } cv;
        #pragma unroll
        for (int j = 0; j < 8; ++j) {
            float w = Wx[(size_t)(224 + qk + j) * G4H + ct * H_SZ + jg * UPW + u];
            cv.h = __float2bfloat16(w);
            bx[ct][j] = cv.s;
        }
    }

    const float bi = bias[0 * H_SZ + jg * UPW + u];
    const float bf = bias[1 * H_SZ + jg * UPW + u];
    const float bg = bias[2 * H_SZ + jg * UPW + u];
    const float bo = bias[3 * H_SZ + jg * UPW + u];

    __syncthreads();   // Wlds ready (hbuf[0] zeroed by init_state)

    const int m0 = wave * 32 + u;        // batch rows this lane feeds
    const int m1 = m0 + 16;
    const bf16_t* bp = Wlds + u * 32 + qk;

    float c0[4] = {0.f, 0.f, 0.f, 0.f};  // cell state: 2 row-tiles x 4 rows
    float c1[4] = {0.f, 0.f, 0.f, 0.f};

    for (int t = 0; t < T_SZ; ++t) {
        const int rb = t & 1;
        const bf16_t* hsrc = hbuf + rb * (B_SZ * H_SZ);
        const bf16_t* a0p = hsrc + m0 * H_SZ + qk;
        const bf16_t* a1p = hsrc + m1 * H_SZ + qk;

        floatx4 acc0[4], acc1[4];
        #pragma unroll
        for (int ct = 0; ct < 4; ++ct) {
            acc0[ct] = (floatx4){0.f, 0.f, 0.f, 0.f};
            acc1[ct] = (floatx4){0.f, 0.f, 0.f, 0.f};
        }

        // ---- Issue h chunks C0 (K 0..7) and C1 (K 8..15): 32 loads in flight.
        bf16x8 fA[16], fB[16];
        #pragma unroll
        for (int kk = 0; kk < 8; ++kk) {
            fA[kk]     = load_h16(a0p + kk * 32);
            fA[8 + kk] = load_h16(a1p + kk * 32);
        }
        #pragma unroll
        for (int kk = 0; kk < 8; ++kk) {
            fB[kk]     = load_h16(a0p + (8 + kk) * 32);
            fB[8 + kk] = load_h16(a1p + (8 + kk) * 32);
        }

        // ---- x_t @ Wx (K=256) runs under the h-load MALL latency. Its
        // compiler-issued loads complete before the counted waits below
        // (each cvt consumes its load), so the vmcnt window stays exact.
        const float* x0p = x + ((size_t)m0 * T_SZ + t) * D_SZ + qk;
        const float* x1p = x + ((size_t)m1 * T_SZ + t) * D_SZ + qk;
        #pragma unroll
        for (int kk = 0; kk < 8; ++kk) {
            bf16x8 a0 = cvt8(x0p + kk * 32);
            bf16x8 a1 = cvt8(x1p + kk * 32);
            #pragma unroll
            for (int ct = 0; ct < 4; ++ct) {
                bf16x8 bb = (kk < 7)
                    ? *(const bf16x8*)(bp + (NKH + kk) * KSTR + ct * 512)
                    : bx[ct];
                acc0[ct] = MFMA(a0, bb, acc0[ct]);
                acc1[ct] = MFMA(a1, bb, acc1[ct]);
            }
        }

        // ---- h @ Wh: 4 chunks, 2-deep pipelined with counted vmcnt.
        // In-order completion: vmcnt(16) with {C_next,C_next2} outstanding
        // guarantees the oldest chunk has fully returned.
        asm volatile("s_waitcnt vmcnt(16)" ::: "memory");   // C0 done
        __builtin_amdgcn_sched_barrier(0);
        #pragma unroll
        for (int kk = 0; kk < 8; ++kk) {
            #pragma unroll
            for (int ct = 0; ct < 4; ++ct) {
                bf16x8 bb = *(const bf16x8*)(bp + kk * KSTR + ct * 512);
                acc0[ct] = MFMA(fA[kk],     bb, acc0[ct]);
                acc1[ct] = MFMA(fA[8 + kk], bb, acc1[ct]);
            }
        }
        #pragma unroll
        for (int kk = 0; kk < 8; ++kk) {                     // issue C2 (K 16..23)
            fA[kk]     = load_h16(a0p + (16 + kk) * 32);
            fA[8 + kk] = load_h16(a1p + (16 + kk) * 32);
        }
        asm volatile("s_waitcnt vmcnt(16)" ::: "memory");   // C1 done
        __builtin_amdgcn_sched_barrier(0);
        #pragma unroll
        for (int kk = 0; kk < 8; ++kk) {
            #pragma unroll
            for (int ct = 0; ct < 4; ++ct) {
                bf16x8 bb = *(const bf16x8*)(bp + (8 + kk) * KSTR + ct * 512);
                acc0[ct] = MFMA(fB[kk],     bb, acc0[ct]);
                acc1[ct] = MFMA(fB[8 + kk], bb, acc1[ct]);
            }
        }
        #pragma unroll
        for (int kk = 0; kk < 8; ++kk) {                     // issue C3 (K 24..31)
            fB[kk]     = load_h16(a0p + (24 + kk) * 32);
            fB[8 + kk] = load_h16(a1p + (24 + kk) * 32);
        }
        asm volatile("s_waitcnt vmcnt(16)" ::: "memory");   // C2 done
        __builtin_amdgcn_sched_barrier(0);
        #pragma unroll
        for (int kk = 0; kk < 8; ++kk) {
            #pragma unroll
            for (int ct = 0; ct < 4; ++ct) {
                bf16x8 bb = *(const bf16x8*)(bp + (16 + kk) * KSTR + ct * 512);
                acc0[ct] = MFMA(fA[kk],     bb, acc0[ct]);
                acc1[ct] = MFMA(fA[8 + kk], bb, acc1[ct]);
            }
        }
        asm volatile("s_waitcnt vmcnt(0)" ::: "memory");    // C3 done
        __builtin_amdgcn_sched_barrier(0);
        #pragma unroll
        for (int kk = 0; kk < 8; ++kk) {
            #pragma unroll
            for (int ct = 0; ct < 4; ++ct) {
                bf16x8 bb = *(const bf16x8*)(bp + (24 + kk) * KSTR + ct * 512);
                acc0[ct] = MFMA(fB[kk],     bb, acc0[ct]);
                acc1[ct] = MFMA(fB[8 + kk], bb, acc1[ct]);
            }
        }

        // ---- Cell update, fully in-register. C/D layout (m89-verified):
        // col = lane&15 (= unit u), row = (lane>>4)*4 + reg. Gate ct: i,f,g,o.
        bf16_t* hdst = hbuf + (rb ^ 1) * (B_SZ * H_SZ);
        #pragma unroll
        for (int r = 0; r < 4; ++r) {
            {   // row-tile 0
                float gi = acc0[0][r] + bi;
                float gf = acc0[1][r] + bf;
                float gg = acc0[2][r] + bg;
                float go = acc0[3][r] + bo;
                float i_ = 1.f / (1.f + __expf(-gi));
                float f_ = 1.f / (1.f + __expf(-gf));
                float g_ = tanhf(gg);
                float o_ = 1.f / (1.f + __expf(-go));
                float cn = f_ * c0[r] + i_ * g_;
                c0[r] = cn;
                float hv = o_ * tanhf(cn);
                union { bf16_t h; unsigned short s; } cv;
                cv.h = __float2bfloat16(hv);
                int row = wave * 32 + (lane >> 4) * 4 + r;
                const bf16_t* p = hdst + (size_t)row * H_SZ + jg * UPW + u;
                unsigned int val = cv.s;
                asm volatile("global_store_short %0, %1, off sc0 sc1"
                             :: "v"(p), "v"(val) : "memory");
            }
            {   // row-tile 1
                float gi = acc1[0][r] + bi;
                float gf = acc1[1][r] + bf;
                float gg = acc1[2][r] + bg;
                float go = acc1[3][r] + bo;
                float i_ = 1.f / (1.f + __expf(-gi));
                float f_ = 1.f / (1.f + __expf(-gf));
                float g_ = tanhf(gg);
                float o_ = 1.f / (1.f + __expf(-go));
                float cn = f_ * c1[r] + i_ * g_;
                c1[r] = cn;
                float hv = o_ * tanhf(cn);
                union { bf16_t h; unsigned short s; } cv;
                cv.h = __float2bfloat16(hv);
                int row = wave * 32 + 16 + (lane >> 4) * 4 + r;
                const bf16_t* p = hdst + (size_t)row * H_SZ + jg * UPW + u;
                unsigned int val = cv.s;
                asm volatile("global_store_short %0, %1, off sc0 sc1"
                             :: "v"(p), "v"(val) : "memory");
            }
        }

        if (t != T_SZ - 1) grid_barrier(flags, (unsigned int)t + 1u);
        // final h reaches memory via kernel-end writeback; decode is stream-ordered
    }
}

// out[128,10] = h_T @ Wd + bd. h_T (bf16) is in hbuf[0]; Wd/bd/out are fp32.
__global__ void decode(const bf16_t* __restrict__ h, const float* __restrict__ Wd,
                       const float* __restrict__ bd, float* __restrict__ out) {
    int b = blockIdx.x;
    int l = threadIdx.x;   // 64
    float acc[O_SZ] = {};
    for (int k = l; k < H_SZ; k += 64) {
        float hv = __bfloat162float(h[b * H_SZ + k]);
        #pragma unroll
        for (int o = 0; o < O_SZ; ++o)
            acc[o] += hv * Wd[k * O_SZ + o];
    }
    #pragma unroll
    for (int o = 0; o < O_SZ; ++o)
        #pragma unroll
        for (int off = 32; off; off >>= 1)
            acc[o] += __shfl_down(acc[o], off);
    if (l == 0)
        #pragma unroll
        for (int o = 0; o < O_SZ; ++o)
            out[b * O_SZ + o] = acc[o] + bd[o];
}

extern "C" void kernel_launch(void* const* d_in, const int* in_sizes, int n_in,
                              void* d_out, int out_size, void* d_ws, size_t ws_size,
                              hipStream_t stream) {
    const float* x  = (const float*)d_in[0];
    const float* Wx = (const float*)d_in[1];
    const float* Wh = (const float*)d_in[2];
    const float* bb = (const float*)d_in[3];
    const float* Wd = (const float*)d_in[4];
    const float* bd = (const float*)d_in[5];
    float* out = (float*)d_out;

    bf16_t* hbuf = (bf16_t*)d_ws;                         // [2][128][1024] = 512 KB
    unsigned int* flags = (unsigned int*)((char*)d_ws + 2 * B_SZ * H_SZ * sizeof(bf16_t));

    constexpr int ldsBytes = KLDS * KSTR * (int)sizeof(bf16_t);   // 159744
    static int attr_once = []() {
        return (int)hipFuncSetAttribute((const void*)lstm_main,
                                        hipFuncAttributeMaxDynamicSharedMemorySize,
                                        ldsBytes);
    }();
    (void)attr_once;

    init_state<<<dim3(256), dim3(256), 0, stream>>>((unsigned int*)d_ws, flags);
    lstm_main<<<dim3(NWG), dim3(256), ldsBytes, stream>>>(x, Wx, Wh, bb, hbuf, flags);
    decode<<<dim3(B_SZ), dim3(64), 0, stream>>>(hbuf, Wd, bd, out);
}

// Round 4
// 7468.449 us; speedup vs baseline: 2.9898x; 2.9898x over previous
//
#include <hip/hip_runtime.h>
#include <hip/hip_bf16.h>

typedef __hip_bfloat16 bf16_t;
typedef short bf16x8 __attribute__((ext_vector_type(8)));   // 8 bf16 bit patterns (4 VGPRs)
typedef float floatx4 __attribute__((ext_vector_type(4)));

#define B_SZ 128
#define T_SZ 1024
#define D_SZ 256
#define H_SZ 1024
#define O_SZ 10
#define G4H  4096
#define NK   40             // total K-steps (32 Wh + 8 Wx)
#define NKH  32             // Wh K-steps
#define CPW  64             // gate cols per WG (4 gates x 16 units)
#define UPW  16             // units per WG
#define RPW  32             // batch rows per WG
#define NWG  256            // 4 row-groups x 64 col-groups, one WG per CU
#define KLDS 23             // Wh K-steps resident in LDS; 23..31 + x streamed from L2
#define KELEM (CPW * 32)    // elements per K-step in Wg/Wlds (2048)
#define HPAD 1032           // hlds row stride in bf16 (2064 B = 129 16B-slots, odd -> spread)
#define WLDS_BYTES (KLDS * KELEM * 2)              // 94208
#define LDS_BYTES  (WLDS_BYTES + RPW * HPAD * 2)   // 94208 + 66048 = 160256
#define FLAG_STRIDE 32      // uints between per-block flags (128 B, own cacheline)

// Zero hbuf[0] (h_{-1} = 0) and the 256 barrier flags.
__global__ void init_state(unsigned int* __restrict__ hz, unsigned int* __restrict__ flags) {
    int idx = blockIdx.x * 256 + threadIdx.x;   // 256 x 256 = 65536
    hz[idx] = 0u;                               // hbuf[0] (128x1024 bf16)
    if (idx < NWG) flags[idx * FLAG_STRIDE] = 0u;
}

// One-time weight preconvert into the PERMUTED column order the main kernel
// consumes contiguously: output col cp = cg*64 + gate*16 + u sources original
// column gate*1024 + cg*16 + u. (r3 bug: wrote original order, so the staged
// 64-col block was gate-i-only columns -> all four gates wrong.)
__global__ void wcvt(const float* __restrict__ Wx, const float* __restrict__ Wh,
                     bf16_t* __restrict__ Wg) {
    long long o = (long long)blockIdx.x * 256 + threadIdx.x;  // 0 .. 5242879
    int kq = (int)(o & 31);
    int cp = (int)((o >> 5) & 4095);   // permuted col
    int kk = (int)(o >> 17);
    int cgI  = cp >> 6;
    int gate = (cp >> 4) & 3;
    int uu   = cp & 15;
    int c    = gate * H_SZ + cgI * UPW + uu;   // original gate-major column
    int k    = kk * 32 + kq;
    float w = (k < H_SZ) ? Wh[(size_t)k * G4H + c]
                         : Wx[(size_t)(k - H_SZ) * G4H + c];
    Wg[o] = __float2bfloat16(w);
}

// Agent-coherent 16B load (bypasses stale L1/L2, reads MALL). r0/r2-proven transport.
__device__ __forceinline__ bf16x8 load_h16(const bf16_t* p) {
    bf16x8 r;
    asm volatile("global_load_dwordx4 %0, %1, off sc0 sc1"
                 : "=v"(r) : "v"(p) : "memory");
    return r;
}
__device__ __forceinline__ void vmwait0() {
    asm volatile("s_waitcnt vmcnt(0)" ::: "memory");
}

// Convert 8 consecutive fp32 to a bf16x8 MFMA fragment (RNE).
__device__ __forceinline__ bf16x8 cvt8(const float* __restrict__ p) {
    floatx4 a = *(const floatx4*)p;
    floatx4 b = *(const floatx4*)(p + 4);
    union { bf16_t h; short s; } u;
    bf16x8 r;
    u.h = __float2bfloat16(a[0]); r[0] = u.s;
    u.h = __float2bfloat16(a[1]); r[1] = u.s;
    u.h = __float2bfloat16(a[2]); r[2] = u.s;
    u.h = __float2bfloat16(a[3]); r[3] = u.s;
    u.h = __float2bfloat16(b[0]); r[4] = u.s;
    u.h = __float2bfloat16(b[1]); r[5] = u.s;
    u.h = __float2bfloat16(b[2]); r[6] = u.s;
    u.h = __float2bfloat16(b[3]); r[7] = u.s;
    return r;
}

#define MFMA(a, b, c) __builtin_amdgcn_mfma_f32_16x16x32_bf16((a), (b), (c), 0, 0, 0)

// ---------------------------------------------------------------------------
// 256 WGs x 256 threads (4 waves), one per CU. WG (rg,cg) owns batch rows
// rg*32..+31 and the 64 permuted gate cols of units cg*16..+15 (x 4 gates).
// Per-CU sc-load traffic: 64 KB/step (4x less than r0) staged once into LDS
// via 16 coalesced 1KB loads/wave in a clean counted-vmcnt window; MFMA reads
// LDS. Permuted col = gate*16+unit puts all 4 gates of a cell in ONE lane ->
// fully in-register cell update (no G staging LDS). Waves split (row-half,
// K-half); K-half partials meet via an 8 KB LDS exchange.
// ---------------------------------------------------------------------------
__global__ void __launch_bounds__(256, 1)
lstm_main(const float* __restrict__ x,      // [B][T][D] fp32
          const float* __restrict__ bias,   // [4H]      fp32
          const bf16_t* __restrict__ Wg,    // [40][4096 perm][32] bf16
          bf16_t* __restrict__ hbuf,        // [2][128][1024] bf16 in d_ws
          unsigned int* __restrict__ flags) {
    extern __shared__ char lds[];
    bf16_t* Wlds = (bf16_t*)lds;                    // [KLDS][64 cols][32 k]
    bf16_t* hlds = (bf16_t*)(lds + WLDS_BYTES);     // [32 rows][1032] padded
    float*  xch  = (float*)(lds + WLDS_BYTES);      // exchange scratch (reuse of hlds)

    const int tid  = threadIdx.x;
    const int lane = tid & 63;
    const int wave = tid >> 6;
    const int rg   = blockIdx.x >> 6;    // row group 0..3
    const int cg   = blockIdx.x & 63;    // col group 0..63
    const int rh   = wave & 1;           // row half (16 rows)
    const int kh   = wave >> 1;          // K half
    const int u    = lane & 15;          // unit within WG / MFMA col
    const int qk   = (lane >> 4) * 8;    // k-offset within 32 (A/B quad)

    // ---- Stage resident weight K-steps 0..22 into LDS (contiguous 16B copies).
    for (int kk = 0; kk < KLDS; ++kk) {
        const bf16_t* src = Wg + (size_t)kk * (G4H * 32) + (size_t)cg * KELEM;
        *(bf16x8*)(Wlds + kk * KELEM + tid * 8) = *(const bf16x8*)(src + tid * 8);
    }
    const float bi = bias[0 * H_SZ + cg * UPW + u];
    const float bf = bias[1 * H_SZ + cg * UPW + u];
    const float bg = bias[2 * H_SZ + cg * UPW + u];
    const float bo = bias[3 * H_SZ + cg * UPW + u];
    __syncthreads();

    // Hoisted fragment base pointers.
    const bf16_t* wb0 = Wlds + u * 32 + qk;                                  // LDS B
    const bf16_t* wsg = Wg + (size_t)(cg * CPW + u) * 32 + qk;               // streamed B
    const bf16_t* ab  = hlds + (size_t)(rh * 16 + u) * HPAD + qk;            // A from hlds

    float cst[4] = {0.f, 0.f, 0.f, 0.f};   // cell state (kh==0 waves own it)
    floatx4 acc[4];

    // x_t @ Wx partial for this wave's (rows, K-half): 4 K-steps, streamed B.
    auto xgemm = [&](int tt) {
        #pragma unroll
        for (int ct = 0; ct < 4; ++ct) acc[ct] = (floatx4){0.f, 0.f, 0.f, 0.f};
        const float* xp = x + ((size_t)(rg * RPW + rh * 16 + u) * T_SZ + tt) * D_SZ
                            + kh * 128 + qk;
        #pragma unroll
        for (int kx = 0; kx < 4; ++kx) {
            bf16x8 a = cvt8(xp + kx * 32);
            const int kk = NKH + kh * 4 + kx;
            #pragma unroll
            for (int ct = 0; ct < 4; ++ct) {
                bf16x8 bb = *(const bf16x8*)(wsg + (size_t)kk * (G4H * 32) + ct * 512);
                acc[ct] = MFMA(a, bb, acc[ct]);
            }
        }
    };

    xgemm(0);   // prologue (x and weights ready at launch; h_{-1}=0 handled below)

    for (int t = 0; t < T_SZ; ++t) {
        if (t > 0) {   // wait: h_{t-1} globally complete (arrive was at end of t-1)
            unsigned int* w = flags + tid * FLAG_STRIDE;
            while (__hip_atomic_load(w, __ATOMIC_RELAXED, __HIP_MEMORY_SCOPE_AGENT)
                   < (unsigned int)t)
                __builtin_amdgcn_s_sleep(8);
            __syncthreads();
        }
        const int rb = t & 1;
        const bf16_t* hsrc = hbuf + rb * (B_SZ * H_SZ);

        // ---- Stage h-tile (32 rows x 2KB = 64 KB) into LDS. Wave w loads rows
        // w*8..w*8+7: 16 instrs x 1KB fully-coalesced sc loads, counted vmcnt
        // (pure asm window - no compiler vector loads outstanding here).
        {
            vmwait0();   // ensure clean vmcnt count (poll/x loads all consumed)
            __builtin_amdgcn_sched_barrier(0);
            const bf16_t* gsrc = hsrc + (size_t)(rg * RPW + wave * 8) * H_SZ + lane * 8;
            bf16_t* lbase = hlds + (size_t)(wave * 8) * HPAD + lane * 8;
            bf16x8 sb[16];
            #pragma unroll
            for (int i = 0; i < 16; ++i) sb[i] = load_h16(gsrc + i * 512);
            asm volatile("s_waitcnt vmcnt(8)" ::: "memory");
            __builtin_amdgcn_sched_barrier(0);
            #pragma unroll
            for (int i = 0; i < 8; ++i)
                *(bf16x8*)(lbase + (i >> 1) * HPAD + (i & 1) * 512) = sb[i];
            vmwait0();
            __builtin_amdgcn_sched_barrier(0);
            #pragma unroll
            for (int i = 8; i < 16; ++i)
                *(bf16x8*)(lbase + (i >> 1) * HPAD + (i & 1) * 512) = sb[i];
            __syncthreads();   // h-LDS ready
        }

        // ---- h @ Wh, this wave's K-half (16 K-steps). kh1's tail streams B from L2.
        if (kh == 0) {
            #pragma unroll
            for (int kk = 0; kk < 16; ++kk) {
                bf16x8 a = *(const bf16x8*)(ab + kk * 32);
                #pragma unroll
                for (int ct = 0; ct < 4; ++ct) {
                    bf16x8 bb = *(const bf16x8*)(wb0 + kk * KELEM + ct * 512);
                    acc[ct] = MFMA(a, bb, acc[ct]);
                }
            }
        } else {
            #pragma unroll
            for (int kk = 16; kk < KLDS; ++kk) {
                bf16x8 a = *(const bf16x8*)(ab + kk * 32);
                #pragma unroll
                for (int ct = 0; ct < 4; ++ct) {
                    bf16x8 bb = *(const bf16x8*)(wb0 + kk * KELEM + ct * 512);
                    acc[ct] = MFMA(a, bb, acc[ct]);
                }
            }
            #pragma unroll
            for (int kk = KLDS; kk < NKH; ++kk) {
                bf16x8 a = *(const bf16x8*)(ab + kk * 32);
                #pragma unroll
                for (int ct = 0; ct < 4; ++ct) {
                    bf16x8 bb = *(const bf16x8*)(wsg + (size_t)kk * (G4H * 32) + ct * 512);
                    acc[ct] = MFMA(a, bb, acc[ct]);
                }
            }
        }

        __syncthreads();   // all waves done reading hlds -> safe to reuse as scratch

        // ---- K-half partial exchange through LDS (8 KB), then in-register cell.
        if (kh == 1) {
            float* s = xch + rh * 1024 + lane * 16;
            #pragma unroll
            for (int ct = 0; ct < 4; ++ct) *(floatx4*)(s + ct * 4) = acc[ct];
        }
        __syncthreads();
        bf16_t* hdst = hbuf + (rb ^ 1) * (B_SZ * H_SZ);
        if (kh == 0) {
            const float* s = xch + rh * 1024 + lane * 16;
            #pragma unroll
            for (int ct = 0; ct < 4; ++ct) acc[ct] += *(const floatx4*)(s + ct * 4);
            // C/D layout (m89-verified): col = lane&15 (= unit), row = (lane>>4)*4 + reg.
            // col-tile ct == gate (i,f,g,o); all 4 gates in-register.
            #pragma unroll
            for (int r = 0; r < 4; ++r) {
                float gi = acc[0][r] + bi;
                float gf = acc[1][r] + bf;
                float gg = acc[2][r] + bg;
                float go = acc[3][r] + bo;
                float i_ = 1.f / (1.f + __expf(-gi));
                float f_ = 1.f / (1.f + __expf(-gf));
                float g_ = tanhf(gg);
                float o_ = 1.f / (1.f + __expf(-go));
                float cn = f_ * cst[r] + i_ * g_;
                cst[r] = cn;
                float hv = o_ * tanhf(cn);
                union { bf16_t h; unsigned short s16; } cv;
                cv.h = __float2bfloat16(hv);
                const bf16_t* p = hdst + (size_t)(rg * RPW + rh * 16 + (lane >> 4) * 4 + r) * H_SZ
                                       + cg * UPW + u;
                unsigned int val = cv.s16;
                asm volatile("global_store_short %0, %1, off sc0 sc1"
                             :: "v"(p), "v"(val) : "memory");
            }
        }
        vmwait0();          // h stores at coherence point
        __syncthreads();    // whole block drained

        if (t != T_SZ - 1) {
            if (tid == 0)   // arrive: one relaxed agent store to own 128B-spaced flag
                __hip_atomic_store(flags + blockIdx.x * FLAG_STRIDE, (unsigned int)(t + 1),
                                   __ATOMIC_RELAXED, __HIP_MEMORY_SCOPE_AGENT);
            xgemm(t + 1);   // x-GEMM(t+1) hides under other WGs' arrival skew
        }
    }
}

// out[128,10] = h_T @ Wd + bd. h_T (bf16) is in hbuf[0]; Wd/bd/out are fp32.
__global__ void decode(const bf16_t* __restrict__ h, const float* __restrict__ Wd,
                       const float* __restrict__ bd, float* __restrict__ out) {
    int b = blockIdx.x;
    int l = threadIdx.x;   // 64
    float acc[O_SZ] = {};
    for (int k = l; k < H_SZ; k += 64) {
        float hv = __bfloat162float(h[b * H_SZ + k]);
        #pragma unroll
        for (int o = 0; o < O_SZ; ++o)
            acc[o] += hv * Wd[k * O_SZ + o];
    }
    #pragma unroll
    for (int o = 0; o < O_SZ; ++o)
        #pragma unroll
        for (int off = 32; off; off >>= 1)
            acc[o] += __shfl_down(acc[o], off);
    if (l == 0)
        #pragma unroll
        for (int o = 0; o < O_SZ; ++o)
            out[b * O_SZ + o] = acc[o] + bd[o];
}

extern "C" void kernel_launch(void* const* d_in, const int* in_sizes, int n_in,
                              void* d_out, int out_size, void* d_ws, size_t ws_size,
                              hipStream_t stream) {
    const float* x  = (const float*)d_in[0];
    const float* Wx = (const float*)d_in[1];
    const float* Wh = (const float*)d_in[2];
    const float* bb = (const float*)d_in[3];
    const float* Wd = (const float*)d_in[4];
    const float* bd = (const float*)d_in[5];
    float* out = (float*)d_out;

    // d_ws layout: hbuf 512 KB | flags 32 KB | (pad) | Wg 10 MB
    bf16_t* hbuf = (bf16_t*)d_ws;
    unsigned int* flags = (unsigned int*)((char*)d_ws + 2 * B_SZ * H_SZ * sizeof(bf16_t));
    bf16_t* Wg = (bf16_t*)((char*)d_ws + (1 << 20));   // 1 MB offset

    static int attr_once = []() {
        return (int)hipFuncSetAttribute((const void*)lstm_main,
                                        hipFuncAttributeMaxDynamicSharedMemorySize,
                                        LDS_BYTES);
    }();
    (void)attr_once;

    init_state<<<dim3(256), dim3(256), 0, stream>>>((unsigned int*)d_ws, flags);
    wcvt<<<dim3((NK * G4H * 32) / 256), dim3(256), 0, stream>>>(Wx, Wh, Wg);
    lstm_main<<<dim3(NWG), dim3(256), LDS_BYTES, stream>>>(x, bb, Wg, hbuf, flags);
    decode<<<dim3(B_SZ), dim3(64), 0, stream>>>(hbuf, Wd, bd, out);
}

// Round 5
// 6998.667 us; speedup vs baseline: 3.1905x; 1.0671x over previous
//
#include <hip/hip_runtime.h>
#include <hip/hip_bf16.h>

typedef __hip_bfloat16 bf16_t;
typedef short bf16x8 __attribute__((ext_vector_type(8)));   // 8 bf16 bit patterns (4 VGPRs)
typedef float floatx4 __attribute__((ext_vector_type(4)));

#define B_SZ 128
#define T_SZ 1024
#define D_SZ 256
#define H_SZ 1024
#define O_SZ 10
#define G4H  4096
#define NK   40             // total K-steps (32 Wh + 8 Wx)
#define NKH  32             // Wh K-steps
#define CPW  64             // gate cols per WG (4 gates x 16 units, permuted)
#define UPW  16             // units per WG
#define RPW  32             // batch rows per WG
#define NWG  256            // 4 row-groups x 64 col-groups, one WG per CU
#define KRES 38             // K-steps resident in LDS (38,39 streamed from L2)
#define KELEM (CPW * 32)    // elements per K-step (2048)
#define WLDS_BYTES (KRES * KELEM * 2)              // 155648
#define LDS_BYTES  (WLDS_BYTES + 8192)             // + 8 KB exchange = 163840 (exact)
#define FLAG_STRIDE 32      // uints between per-block flags (128 B, own cacheline)

// Zero hbuf[0] (h_{-1} = 0) and the 256 barrier flags.
__global__ void init_state(unsigned int* __restrict__ hz, unsigned int* __restrict__ flags) {
    int idx = blockIdx.x * 256 + threadIdx.x;   // 256 x 256 = 65536
    hz[idx] = 0u;                               // hbuf[0] (128x1024 bf16)
    if (idx < NWG) flags[idx * FLAG_STRIDE] = 0u;
}

// One-time weight preconvert into the PERMUTED column order the main kernel
// consumes contiguously: output col cp = cg*64 + gate*16 + u sources original
// column gate*1024 + cg*16 + u. (r4-verified.)
__global__ void wcvt(const float* __restrict__ Wx, const float* __restrict__ Wh,
                     bf16_t* __restrict__ Wg) {
    long long o = (long long)blockIdx.x * 256 + threadIdx.x;  // 0 .. 5242879
    int kq = (int)(o & 31);
    int cp = (int)((o >> 5) & 4095);   // permuted col
    int kk = (int)(o >> 17);
    int cgI  = cp >> 6;
    int gate = (cp >> 4) & 3;
    int uu   = cp & 15;
    int c    = gate * H_SZ + cgI * UPW + uu;   // original gate-major column
    int k    = kk * 32 + kq;
    float w = (k < H_SZ) ? Wh[(size_t)k * G4H + c]
                         : Wx[(size_t)(k - H_SZ) * G4H + c];
    Wg[o] = __float2bfloat16(w);
}

// Agent-coherent 16B load (bypasses stale L1/L2, reads MALL). r0/r4-proven transport.
__device__ __forceinline__ bf16x8 load_h16(const bf16_t* p) {
    bf16x8 r;
    asm volatile("global_load_dwordx4 %0, %1, off sc0 sc1"
                 : "=v"(r) : "v"(p) : "memory");
    return r;
}
__device__ __forceinline__ void vmwait0() {
    asm volatile("s_waitcnt vmcnt(0)" ::: "memory");
}

// Convert 8 consecutive fp32 to a bf16x8 MFMA fragment (RNE).
__device__ __forceinline__ bf16x8 cvt8(const float* __restrict__ p) {
    floatx4 a = *(const floatx4*)p;
    floatx4 b = *(const floatx4*)(p + 4);
    union { bf16_t h; short s; } u;
    bf16x8 r;
    u.h = __float2bfloat16(a[0]); r[0] = u.s;
    u.h = __float2bfloat16(a[1]); r[1] = u.s;
    u.h = __float2bfloat16(a[2]); r[2] = u.s;
    u.h = __float2bfloat16(a[3]); r[3] = u.s;
    u.h = __float2bfloat16(b[0]); r[4] = u.s;
    u.h = __float2bfloat16(b[1]); r[5] = u.s;
    u.h = __float2bfloat16(b[2]); r[6] = u.s;
    u.h = __float2bfloat16(b[3]); r[7] = u.s;
    return r;
}

#define MFMA(a, b, c) __builtin_amdgcn_mfma_f32_16x16x32_bf16((a), (b), (c), 0, 0, 0)

// ---------------------------------------------------------------------------
// 256 WGs x 256 threads (4 waves), one per CU. WG (rg,cg) owns batch rows
// rg*32..+31 and the 64 permuted gate cols of units cg*16..+15.
// vs r4: (1) NO h-LDS staging - A-fragments load sc directly to registers,
// chunk-pipelined (8 in flight while 8 compute); the staging round-trip had
// zero reuse. (2) Freed 64 KB LDS -> 38/40 weight K-steps resident. (3) The 4
// row-groups are INDEPENDENT sub-problems (producers of rg-rows = (rg,*)) ->
// per-rg 64-WG barriers instead of one global 256-WG barrier.
// ---------------------------------------------------------------------------
__global__ void __launch_bounds__(256, 1)
lstm_main(const float* __restrict__ x,      // [B][T][D] fp32
          const float* __restrict__ bias,   // [4H]      fp32
          const bf16_t* __restrict__ Wg,    // [40][4096 perm][32] bf16
          bf16_t* __restrict__ hbuf,        // [2][128][1024] bf16 in d_ws
          unsigned int* __restrict__ flags) {
    extern __shared__ char lds[];
    bf16_t* Wlds = (bf16_t*)lds;                    // [KRES][64 cols][32 k]
    float*  xch  = (float*)(lds + WLDS_BYTES);      // 8 KB K-half exchange

    const int tid  = threadIdx.x;
    const int lane = tid & 63;
    const int wave = tid >> 6;
    const int rg   = blockIdx.x >> 6;    // row group 0..3
    const int cg   = blockIdx.x & 63;    // col group 0..63
    const int rh   = wave & 1;           // row half (16 rows)
    const int kh   = wave >> 1;          // K half
    const int u    = lane & 15;          // unit within WG / MFMA col & A-row
    const int qk   = (lane >> 4) * 8;    // k-offset within 32 (A/B quad)

    // ---- Stage resident weight K-steps 0..37 into LDS (contiguous 16B copies).
    for (int f = tid * 8; f < KRES * KELEM; f += 256 * 8) {
        int kk = f / KELEM, e = f - kk * KELEM;
        *(bf16x8*)(Wlds + f) =
            *(const bf16x8*)(Wg + (size_t)kk * (G4H * 32) + (size_t)cg * KELEM + e);
    }
    const float bi = bias[0 * H_SZ + cg * UPW + u];
    const float bf = bias[1 * H_SZ + cg * UPW + u];
    const float bg = bias[2 * H_SZ + cg * UPW + u];
    const float bo = bias[3 * H_SZ + cg * UPW + u];
    __syncthreads();

    // Hoisted pointers. B-frag: col = lane&15, k-quad = qk (m89-verified).
    const bf16_t* wb0 = Wlds + u * 32 + qk;                       // LDS B base
    const bf16_t* wsg = Wg + (size_t)(cg * CPW + u) * 32 + qk;    // streamed B base
    const int arow = rg * RPW + rh * 16 + u;                      // this lane's A row

    float cst[4] = {0.f, 0.f, 0.f, 0.f};   // cell state (kh==0 waves own it)
    floatx4 acc[4];

    // x_t @ Wx partial for this wave's (rows, x-K-half). kh0: kk 32..35 (LDS);
    // kh1: kk 36..37 (LDS) + 38..39 (streamed from L2).
    auto xgemm = [&](int tt) {
        #pragma unroll
        for (int ct = 0; ct < 4; ++ct) acc[ct] = (floatx4){0.f, 0.f, 0.f, 0.f};
        const float* xp = x + ((size_t)arow * T_SZ + tt) * D_SZ + kh * 128 + qk;
        #pragma unroll
        for (int kx = 0; kx < 4; ++kx) {
            bf16x8 a = cvt8(xp + kx * 32);
            const int kk = NKH + kh * 4 + kx;
            #pragma unroll
            for (int ct = 0; ct < 4; ++ct) {
                bf16x8 bb = (kk < KRES)
                    ? *(const bf16x8*)(wb0 + kk * KELEM + ct * 512)
                    : *(const bf16x8*)(wsg + (size_t)kk * (G4H * 32) + ct * 512);
                acc[ct] = MFMA(a, bb, acc[ct]);
            }
        }
    };

    xgemm(0);   // prologue (x and weights ready at launch; h_{-1}=0 from init_state)

    const int kb = kh * 16;   // this wave's Wh K-half base

    for (int t = 0; t < T_SZ; ++t) {
        if (t > 0) {   // per-rg barrier wait: poll the 64 flags of OUR row group
            unsigned int* w = flags + (rg * 64 + (tid & 63)) * FLAG_STRIDE;
            while (__hip_atomic_load(w, __ATOMIC_RELAXED, __HIP_MEMORY_SCOPE_AGENT)
                   < (unsigned int)t)
                __builtin_amdgcn_s_sleep(8);
            __syncthreads();
        }
        const int rb = t & 1;
        const bf16_t* ap = hbuf + rb * (B_SZ * H_SZ) + (size_t)arow * H_SZ + qk;

        // ---- h @ Wh, direct sc A-loads, 2-chunk pipeline (8 frags in flight
        // while 8 compute). Clean vmcnt window: all prior vmem consumed.
        vmwait0();
        __builtin_amdgcn_sched_barrier(0);
        bf16x8 fA[8], fB[8];
        #pragma unroll
        for (int kk = 0; kk < 8; ++kk) fA[kk] = load_h16(ap + (kb + kk) * 32);
        #pragma unroll
        for (int kk = 0; kk < 8; ++kk) fB[kk] = load_h16(ap + (kb + 8 + kk) * 32);
        asm volatile("s_waitcnt vmcnt(8)" ::: "memory");   // chunk 0 landed
        __builtin_amdgcn_sched_barrier(0);
        #pragma unroll
        for (int kk = 0; kk < 8; ++kk) {
            #pragma unroll
            for (int ct = 0; ct < 4; ++ct) {
                bf16x8 bb = *(const bf16x8*)(wb0 + (kb + kk) * KELEM + ct * 512);
                acc[ct] = MFMA(fA[kk], bb, acc[ct]);
            }
        }
        vmwait0();                                          // chunk 1 landed
        __builtin_amdgcn_sched_barrier(0);
        #pragma unroll
        for (int kk = 0; kk < 8; ++kk) {
            #pragma unroll
            for (int ct = 0; ct < 4; ++ct) {
                bf16x8 bb = *(const bf16x8*)(wb0 + (kb + 8 + kk) * KELEM + ct * 512);
                acc[ct] = MFMA(fB[kk], bb, acc[ct]);
            }
        }

        // ---- K-half partial exchange through LDS (8 KB), then in-register cell.
        if (kh == 1) {
            float* s = xch + rh * 1024 + lane * 16;
            #pragma unroll
            for (int ct = 0; ct < 4; ++ct) *(floatx4*)(s + ct * 4) = acc[ct];
        }
        __syncthreads();
        bf16_t* hdst = hbuf + (rb ^ 1) * (B_SZ * H_SZ);
        if (kh == 0) {
            const float* s = xch + rh * 1024 + lane * 16;
            #pragma unroll
            for (int ct = 0; ct < 4; ++ct) acc[ct] += *(const floatx4*)(s + ct * 4);
            // C/D layout (m89-verified): col = lane&15 (= unit), row = (lane>>4)*4+reg.
            // col-tile ct == gate (i,f,g,o) via the wcvt permutation.
            #pragma unroll
            for (int r = 0; r < 4; ++r) {
                float gi = acc[0][r] + bi;
                float gf = acc[1][r] + bf;
                float gg = acc[2][r] + bg;
                float go = acc[3][r] + bo;
                float i_ = 1.f / (1.f + __expf(-gi));
                float f_ = 1.f / (1.f + __expf(-gf));
                float g_ = tanhf(gg);
                float o_ = 1.f / (1.f + __expf(-go));
                float cn = f_ * cst[r] + i_ * g_;
                cst[r] = cn;
                float hv = o_ * tanhf(cn);
                union { bf16_t h; unsigned short s16; } cv;
                cv.h = __float2bfloat16(hv);
                const bf16_t* p = hdst
                    + (size_t)(rg * RPW + rh * 16 + (lane >> 4) * 4 + r) * H_SZ
                    + cg * UPW + u;
                unsigned int val = cv.s16;
                asm volatile("global_store_short %0, %1, off sc0 sc1"
                             :: "v"(p), "v"(val) : "memory");
            }
        }
        vmwait0();          // h stores at coherence point
        __syncthreads();    // whole block drained

        if (t != T_SZ - 1) {
            if (tid == 0)   // arrive: one relaxed agent store to own 128B-spaced flag
                __hip_atomic_store(flags + blockIdx.x * FLAG_STRIDE, (unsigned int)(t + 1),
                                   __ATOMIC_RELAXED, __HIP_MEMORY_SCOPE_AGENT);
            xgemm(t + 1);   // x-GEMM(t+1) hides under other WGs' arrival skew
        }
    }
}

// out[128,10] = h_T @ Wd + bd. h_T (bf16) is in hbuf[0]; Wd/bd/out are fp32.
__global__ void decode(const bf16_t* __restrict__ h, const float* __restrict__ Wd,
                       const float* __restrict__ bd, float* __restrict__ out) {
    int b = blockIdx.x;
    int l = threadIdx.x;   // 64
    float acc[O_SZ] = {};
    for (int k = l; k < H_SZ; k += 64) {
        float hv = __bfloat162float(h[b * H_SZ + k]);
        #pragma unroll
        for (int o = 0; o < O_SZ; ++o)
            acc[o] += hv * Wd[k * O_SZ + o];
    }
    #pragma unroll
    for (int o = 0; o < O_SZ; ++o)
        #pragma unroll
        for (int off = 32; off; off >>= 1)
            acc[o] += __shfl_down(acc[o], off);
    if (l == 0)
        #pragma unroll
        for (int o = 0; o < O_SZ; ++o)
            out[b * O_SZ + o] = acc[o] + bd[o];
}

extern "C" void kernel_launch(void* const* d_in, const int* in_sizes, int n_in,
                              void* d_out, int out_size, void* d_ws, size_t ws_size,
                              hipStream_t stream) {
    const float* x  = (const float*)d_in[0];
    const float* Wx = (const float*)d_in[1];
    const float* Wh = (const float*)d_in[2];
    const float* bb = (const float*)d_in[3];
    const float* Wd = (const float*)d_in[4];
    const float* bd = (const float*)d_in[5];
    float* out = (float*)d_out;

    // d_ws layout: hbuf 512 KB | flags 32 KB | (pad) | Wg 10 MB
    bf16_t* hbuf = (bf16_t*)d_ws;
    unsigned int* flags = (unsigned int*)((char*)d_ws + 2 * B_SZ * H_SZ * sizeof(bf16_t));
    bf16_t* Wg = (bf16_t*)((char*)d_ws + (1 << 20));   // 1 MB offset

    static int attr_once = []() {
        return (int)hipFuncSetAttribute((const void*)lstm_main,
                                        hipFuncAttributeMaxDynamicSharedMemorySize,
                                        LDS_BYTES);
    }();
    (void)attr_once;

    init_state<<<dim3(256), dim3(256), 0, stream>>>((unsigned int*)d_ws, flags);
    wcvt<<<dim3((NK * G4H * 32) / 256), dim3(256), 0, stream>>>(Wx, Wh, Wg);
    lstm_main<<<dim3(NWG), dim3(256), LDS_BYTES, stream>>>(x, bb, Wg, hbuf, flags);
    decode<<<dim3(B_SZ), dim3(64), 0, stream>>>(hbuf, Wd, bd, out);
}

// Round 6
// 5183.717 us; speedup vs baseline: 4.3076x; 1.3501x over previous
//
#include <hip/hip_runtime.h>
#include <hip/hip_bf16.h>

typedef __hip_bfloat16 bf16_t;
typedef short bf16x8 __attribute__((ext_vector_type(8)));   // 8 bf16 bit patterns (4 VGPRs)
typedef float floatx4 __attribute__((ext_vector_type(4)));

#define B_SZ 128
#define T_SZ 1024
#define D_SZ 256
#define H_SZ 1024
#define O_SZ 10
#define G4H  4096
#define NK   40             // total K-steps (32 Wh + 8 Wx)
#define NRG  8              // row groups (16 rows each)
#define NCG  32             // col groups (128 permuted cols each)
#define RPW  16             // batch rows per WG (one MFMA M-tile)
#define CPW  128            // permuted gate cols per WG (32 units x 4 gates)
#define NWG  256
#define KELEM (CPW * 32)    // elems per K-step block (4096 = 8 KB)
#define NSLOT 16            // LDS-resident K-step slots (4 per wave)
#define WLDS_BYTES (NSLOT * KELEM * 2)          // 131072
#define G_FLOATS   (4 * 8 * 4 * 64)             // 8192 floats = 32 KB
#define LDS_BYTES  (WLDS_BYTES + G_FLOATS * 4)  // 163840 (exact 160 KB)
#define FLAG_STRIDE 32      // uints between per-block flags (128 B, own cacheline)

// Zero hbuf[0] (h_{-1} = 0) and the 256 barrier flags.
__global__ void init_state(unsigned int* __restrict__ hz, unsigned int* __restrict__ flags) {
    int idx = blockIdx.x * 256 + threadIdx.x;   // 256 x 256 = 65536
    hz[idx] = 0u;                               // hbuf[0] (128x1024 bf16)
    if (idx < NWG) flags[idx * FLAG_STRIDE] = 0u;
}

// One-time weight preconvert, PERMUTED for the 128-col WG tiles:
// output col cp = cg*128 + c', c' = gate*32 + w  sources original column
// gate*1024 + cg*32 + w.  Wg layout: [kk][4096 perm cols][32 k] bf16.
__global__ void wcvt(const float* __restrict__ Wx, const float* __restrict__ Wh,
                     bf16_t* __restrict__ Wg) {
    long long o = (long long)blockIdx.x * 256 + threadIdx.x;  // 0 .. 5242879
    int kq  = (int)(o & 31);
    int cp  = (int)((o >> 5) & 4095);
    int kk  = (int)(o >> 17);
    int cgI = cp >> 7;          // 0..31
    int cpr = cp & 127;         // c' within WG
    int g   = cpr >> 5;         // gate
    int w   = cpr & 31;         // unit within WG
    int c   = g * H_SZ + cgI * 32 + w;   // original gate-major column
    int k   = kk * 32 + kq;
    float val = (k < H_SZ) ? Wh[(size_t)k * G4H + c]
                           : Wx[(size_t)(k - H_SZ) * G4H + c];
    Wg[o] = __float2bfloat16(val);
}

// Agent-coherent 16B load (bypasses stale L1/L2, reads MALL). r0/r4/r5-proven.
__device__ __forceinline__ bf16x8 load_h16(const bf16_t* p) {
    bf16x8 r;
    asm volatile("global_load_dwordx4 %0, %1, off sc0 sc1"
                 : "=v"(r) : "v"(p) : "memory");
    return r;
}
__device__ __forceinline__ void vmwait0() {
    asm volatile("s_waitcnt vmcnt(0)" ::: "memory");
}

// Convert 8 consecutive fp32 to a bf16x8 MFMA fragment (RNE).
__device__ __forceinline__ bf16x8 cvt8(const float* __restrict__ p) {
    floatx4 a = *(const floatx4*)p;
    floatx4 b = *(const floatx4*)(p + 4);
    union { bf16_t h; short s; } u;
    bf16x8 r;
    u.h = __float2bfloat16(a[0]); r[0] = u.s;
    u.h = __float2bfloat16(a[1]); r[1] = u.s;
    u.h = __float2bfloat16(a[2]); r[2] = u.s;
    u.h = __float2bfloat16(a[3]); r[3] = u.s;
    u.h = __float2bfloat16(b[0]); r[4] = u.s;
    u.h = __float2bfloat16(b[1]); r[5] = u.s;
    u.h = __float2bfloat16(b[2]); r[6] = u.s;
    u.h = __float2bfloat16(b[3]); r[7] = u.s;
    return r;
}

#define MFMA(a, b, c) __builtin_amdgcn_mfma_f32_16x16x32_bf16((a), (b), (c), 0, 0, 0)

// ---------------------------------------------------------------------------
// 256 WGs x 256 threads (4 waves, 1 wave/SIMD -> 512 VGPR budget). WG (rg,cg)
// owns batch rows rg*16..+15 and 128 permuted gate cols (units cg*32..+31).
// Per-CU sc h-traffic: 16 rows x 2 KB = 32 KB/step (2x less than r5).
// Weights are loaded ONCE before the t-loop: 16 K-steps in 128 KB LDS
// (4/wave, chunk-XOR swizzled -> conflict-free B-reads) + 6 K-steps/wave in
// 192 VGPRs of persistent register fragments. Zero per-step weight traffic.
// Waves K-split 4 ways (8 Wh + 2 Wx steps each); partials meet in a 32 KB
// LDS G buffer (conflict-free layout); cell update spread over all threads.
// ---------------------------------------------------------------------------
__global__ void __launch_bounds__(256, 1)
lstm_main(const float* __restrict__ x,      // [B][T][D] fp32
          const float* __restrict__ bias,   // [4H]      fp32
          const bf16_t* __restrict__ Wg,    // [40][4096 perm][32] bf16
          bf16_t* __restrict__ hbuf,        // [2][128][1024] bf16 in d_ws
          unsigned int* __restrict__ flags) {
    extern __shared__ char lds[];
    bf16_t* Wlds = (bf16_t*)lds;                 // [16 slots][4096] swizzled
    float*  Gf   = (float*)(lds + WLDS_BYTES);   // [4 wv][8 ct][4 r][64]

    const int tid  = threadIdx.x;
    const int lane = tid & 63;
    const int wv   = tid >> 6;
    const int rg   = blockIdx.x >> 5;    // row group 0..7
    const int cg   = blockIdx.x & 31;    // col group 0..31
    const int u    = lane & 15;          // MFMA col-in-tile / A row
    const int q    = lane >> 4;          // quad
    const int qk   = q * 8;              // k-offset within 32

    // ---- Stage 16 LDS weight slots: slot s holds Wh K-step (s>>2)*8 + (s&3)
    // (wave w's steps w*8..w*8+3). Chunk-XOR swizzle (cc ^ (cc>>3)&3) spreads
    // the stride-64B B-read pattern across all 8 bank slots (free 2-way tier).
    for (int s = 0; s < NSLOT; ++s) {
        int gk = (s >> 2) * 8 + (s & 3);
        const bf16_t* src = Wg + (size_t)gk * (G4H * 32) + (size_t)cg * KELEM;
        bf16_t* dst = Wlds + s * KELEM;
        for (int cc = tid; cc < 512; cc += 256) {
            int cs = cc ^ ((cc >> 3) & 3);
            *(bf16x8*)(dst + cs * 8) = *(const bf16x8*)(src + cc * 8);
        }
    }

    // ---- Persistent register B-fragments: wave wv owns Wh steps wv*8+4..+7
    // (breg[0..3]) and Wx steps 32+wv*2, +1 (breg[4..5]). 192 VGPRs.
    bf16x8 breg[6][8];
    const bf16_t* wgp = Wg + (size_t)(cg * CPW + u) * 32 + qk;
    #pragma unroll
    for (int i = 0; i < 4; ++i) {
        const bf16_t* p = wgp + (size_t)(wv * 8 + 4 + i) * (G4H * 32);
        #pragma unroll
        for (int ct = 0; ct < 8; ++ct)
            breg[i][ct] = *(const bf16x8*)(p + ct * 512);
    }
    #pragma unroll
    for (int i = 0; i < 2; ++i) {
        const bf16_t* p = wgp + (size_t)(32 + wv * 2 + i) * (G4H * 32);
        #pragma unroll
        for (int ct = 0; ct < 8; ++ct)
            breg[4 + i][ct] = *(const bf16x8*)(p + ct * 512);
    }

    // ---- Cell-phase constants: thread owns cells (crow, w0) and (crow, w0+1).
    const int crow = tid >> 4;           // 0..15
    const int w0   = (tid & 15) * 2;     // even unit within WG
    float bs[2][4];
    #pragma unroll
    for (int s2 = 0; s2 < 2; ++s2)
        #pragma unroll
        for (int g = 0; g < 4; ++g)
            bs[s2][g] = bias[g * H_SZ + cg * 32 + w0 + s2];

    __syncthreads();   // Wlds ready

    const int arow = rg * RPW + u;       // this lane's global A row
    float cs0 = 0.f, cs1 = 0.f;          // cell state
    floatx4 acc[8];

    // x_t @ Wx partial for this wave's 2 x-K-steps (B in registers).
    auto xgemm = [&](int tt) {
        const float* xp = x + ((size_t)arow * T_SZ + tt) * D_SZ + wv * 64 + qk;
        #pragma unroll
        for (int i = 0; i < 2; ++i) {
            bf16x8 a = cvt8(xp + i * 32);
            #pragma unroll
            for (int ct = 0; ct < 8; ++ct)
                acc[ct] = MFMA(a, breg[4 + i][ct], acc[ct]);
        }
    };

    #pragma unroll
    for (int ct = 0; ct < 8; ++ct) acc[ct] = (floatx4){0.f, 0.f, 0.f, 0.f};
    xgemm(0);   // prologue

    for (int t = 0; t < T_SZ; ++t) {
        if (t > 0) {   // per-rg barrier: poll the 32 flags of our row group
            unsigned int* w = flags + (rg * 32 + (tid & 31)) * FLAG_STRIDE;
            while (__hip_atomic_load(w, __ATOMIC_RELAXED, __HIP_MEMORY_SCOPE_AGENT)
                   < (unsigned int)t)
                __builtin_amdgcn_s_sleep(8);
            __syncthreads();
        }
        const int rb = t & 1;
        const bf16_t* ap = hbuf + rb * (B_SZ * H_SZ) + (size_t)arow * H_SZ + qk;

        // ---- h A-frags: wave's 8 Wh K-steps, direct sc loads, 2-chunk pipeline.
        vmwait0();
        __builtin_amdgcn_sched_barrier(0);
        bf16x8 fA[8];
        #pragma unroll
        for (int i = 0; i < 8; ++i) fA[i] = load_h16(ap + (wv * 8 + i) * 32);
        asm volatile("s_waitcnt vmcnt(4)" ::: "memory");   // fA[0..3] landed
        __builtin_amdgcn_sched_barrier(0);
        #pragma unroll
        for (int i = 0; i < 4; ++i) {                      // LDS-resident B
            #pragma unroll
            for (int ct = 0; ct < 8; ++ct) {
                int chunk = ct * 64 + u * 4 + q;
                chunk ^= (chunk >> 3) & 3;                 // de-conflict swizzle
                bf16x8 bb = *(const bf16x8*)(Wlds + (wv * 4 + i) * KELEM + chunk * 8);
                acc[ct] = MFMA(fA[i], bb, acc[ct]);
            }
        }
        vmwait0();                                          // fA[4..7] landed
        __builtin_amdgcn_sched_barrier(0);
        #pragma unroll
        for (int i = 0; i < 4; ++i) {                      // register-resident B
            #pragma unroll
            for (int ct = 0; ct < 8; ++ct)
                acc[ct] = MFMA(fA[4 + i], breg[i][ct], acc[ct]);
        }

        // ---- Partial exchange: conflict-free G layout [wv][ct][r][lane^swz].
        #pragma unroll
        for (int ct = 0; ct < 8; ++ct)
            #pragma unroll
            for (int r = 0; r < 4; ++r)
                Gf[((wv * 8 + ct) * 4 + r) * 64 + (lane ^ (r * 16))] = acc[ct][r];
        __syncthreads();

        // ---- Cell update: all 256 threads, 2 cells each, sum 4 wave-partials.
        bf16_t* hdst = hbuf + (rb ^ 1) * (B_SZ * H_SZ);
        float hv[2];
        #pragma unroll
        for (int s2 = 0; s2 < 2; ++s2) {
            int w  = w0 + s2;
            int ctb = w >> 4, uu = w & 15;
            int r  = crow & 3;
            int sl = ((crow >> 2) * 16 + uu) ^ (r * 16);
            float g4[4];
            #pragma unroll
            for (int g = 0; g < 4; ++g) {
                int base = ((g * 2 + ctb) * 4 + r) * 64 + sl;
                g4[g] = Gf[base] + Gf[base + 2048] + Gf[base + 4096] + Gf[base + 6144]
                      + bs[s2][g];
            }
            float i_ = 1.f / (1.f + __expf(-g4[0]));
            float f_ = 1.f / (1.f + __expf(-g4[1]));
            float g_ = tanhf(g4[2]);
            float o_ = 1.f / (1.f + __expf(-g4[3]));
            float cn = f_ * (s2 ? cs1 : cs0) + i_ * g_;
            if (s2) cs1 = cn; else cs0 = cn;
            hv[s2] = o_ * tanhf(cn);
        }
        union { unsigned int u32; bf16_t h2[2]; } pk;
        pk.h2[0] = __float2bfloat16(hv[0]);
        pk.h2[1] = __float2bfloat16(hv[1]);
        __hip_atomic_store((unsigned int*)(hdst + (size_t)(rg * RPW + crow) * H_SZ
                                           + cg * 32 + w0), pk.u32,
                           __ATOMIC_RELAXED, __HIP_MEMORY_SCOPE_AGENT);

        vmwait0();          // h stores at coherence point
        __syncthreads();    // whole block drained (also guards Gf reuse)

        if (t != T_SZ - 1) {
            if (tid == 0)   // arrive
                __hip_atomic_store(flags + blockIdx.x * FLAG_STRIDE, (unsigned int)(t + 1),
                                   __ATOMIC_RELAXED, __HIP_MEMORY_SCOPE_AGENT);
            #pragma unroll
            for (int ct = 0; ct < 8; ++ct) acc[ct] = (floatx4){0.f, 0.f, 0.f, 0.f};
            xgemm(t + 1);   // hides under other WGs' arrival skew
        }
    }
}

// out[128,10] = h_T @ Wd + bd. h_T (bf16) is in hbuf[0]; Wd/bd/out are fp32.
__global__ void decode(const bf16_t* __restrict__ h, const float* __restrict__ Wd,
                       const float* __restrict__ bd, float* __restrict__ out) {
    int b = blockIdx.x;
    int l = threadIdx.x;   // 64
    float acc[O_SZ] = {};
    for (int k = l; k < H_SZ; k += 64) {
        float hv = __bfloat162float(h[b * H_SZ + k]);
        #pragma unroll
        for (int o = 0; o < O_SZ; ++o)
            acc[o] += hv * Wd[k * O_SZ + o];
    }
    #pragma unroll
    for (int o = 0; o < O_SZ; ++o)
        #pragma unroll
        for (int off = 32; off; off >>= 1)
            acc[o] += __shfl_down(acc[o], off);
    if (l == 0)
        #pragma unroll
        for (int o = 0; o < O_SZ; ++o)
            out[b * O_SZ + o] = acc[o] + bd[o];
}

extern "C" void kernel_launch(void* const* d_in, const int* in_sizes, int n_in,
                              void* d_out, int out_size, void* d_ws, size_t ws_size,
                              hipStream_t stream) {
    const float* x  = (const float*)d_in[0];
    const float* Wx = (const float*)d_in[1];
    const float* Wh = (const float*)d_in[2];
    const float* bb = (const float*)d_in[3];
    const float* Wd = (const float*)d_in[4];
    const float* bd = (const float*)d_in[5];
    float* out = (float*)d_out;

    // d_ws layout: hbuf 512 KB | flags 32 KB | (pad) | Wg 10 MB
    bf16_t* hbuf = (bf16_t*)d_ws;
    unsigned int* flags = (unsigned int*)((char*)d_ws + 2 * B_SZ * H_SZ * sizeof(bf16_t));
    bf16_t* Wg = (bf16_t*)((char*)d_ws + (1 << 20));   // 1 MB offset

    static int attr_once = []() {
        return (int)hipFuncSetAttribute((const void*)lstm_main,
                                        hipFuncAttributeMaxDynamicSharedMemorySize,
                                        LDS_BYTES);
    }();
    (void)attr_once;

    init_state<<<dim3(256), dim3(256), 0, stream>>>((unsigned int*)d_ws, flags);
    wcvt<<<dim3((NK * G4H * 32) / 256), dim3(256), 0, stream>>>(Wx, Wh, Wg);
    lstm_main<<<dim3(NWG), dim3(256), LDS_BYTES, stream>>>(x, bb, Wg, hbuf, flags);
    decode<<<dim3(B_SZ), dim3(64), 0, stream>>>(hbuf, Wd, bd, out);
}